// Round 7
// baseline (254.470 us; speedup 1.0000x reference)
//
#include <hip/hip_runtime.h>

typedef _Float16 f16;
typedef _Float16 f16x2 __attribute__((ext_vector_type(2)));
typedef _Float16 f16x4 __attribute__((ext_vector_type(4)));
typedef _Float16 f16x8 __attribute__((ext_vector_type(8)));
typedef float f32x4 __attribute__((ext_vector_type(4)));

#define L_N 2500
#define B_N 1024
#define ROWSTRIDE 30000      // 12*2500, channel 0 only
#define NPATCH 50
#define PATCH 50
#define KP 2560              // K padded to 80*32 (pad region zeroed)
#define NB 2560              // 1280 bins * 2 (cos,sin) rows
#define ZSPLIT 8
#define KS_PER_Z 10          // 80 K32-steps / 8

#define TWOPI_F 6.28318530717958647692f
#define RAD_PER_PH (6.283185307179586476925286766559 / 2500.0)

// workspace layout (bytes); total ~27.5 MB
#define OFF_XH 0
#define SZ_XH (B_N * KP * 2)          // 5,242,880
#define OFF_W  (OFF_XH + SZ_XH)
#define SZ_W   (NB * KP * 2)          // 13,107,200
#define OFF_C  (OFF_W + SZ_W)
#define SZ_C   (B_N * NB * 4)         // 10,485,760

// prep-kernel block ranges
#define PB_X    B_N                    // 1024 blocks: x -> f16
#define PB_W    1280                   // 1280 blocks: twiddles
#define PB_Z    (SZ_C / 16 / 256)      // 2560 blocks: zero C
#define PB_TOT  (PB_X + PB_W + PB_Z)   // 4864

#define GLOAD16(gp, lp) __builtin_amdgcn_global_load_lds( \
    (const __attribute__((address_space(1))) unsigned int*)(gp), \
    (__attribute__((address_space(3))) unsigned int*)(lp), 16, 0, 0)

// ------- fused prep: gen_x | gen_w | zero_c by blockIdx range -------
__global__ __launch_bounds__(256)
void prep(const float* __restrict__ x, f16* __restrict__ Xh,
          f16* __restrict__ W, float4* __restrict__ C4) {
    const int b = blockIdx.x, tid = threadIdx.x;
    if (b < PB_X) {
        const int row = b;
#pragma unroll
        for (int i = 0; i < 3; ++i) {
            int slot = tid + 256 * i;                 // float4 slot, 640 per row
            if (slot < 640) {
                float4 v = make_float4(0.f, 0.f, 0.f, 0.f);
                if (slot < 625)                       // 2500/4 == 625 exactly
                    v = *reinterpret_cast<const float4*>(x + (size_t)row * ROWSTRIDE + slot * 4);
                f16x4 h = { (f16)v.x, (f16)v.y, (f16)v.z, (f16)v.w };
                *reinterpret_cast<f16x4*>(Xh + (size_t)row * KP + slot * 4) = h;
            }
        }
    } else if (b < PB_X + PB_W) {
        const int bin = b - PB_X;                     // 0..1279
#pragma unroll
        for (int i = 0; i < 5; ++i) {                 // KP/2/256 == 5
            int t2 = tid + 256 * i;                   // pair index
            int t = 2 * t2;
            float c0 = 0.f, s0 = 0.f, c1 = 0.f, s1 = 0.f;
            if (t < L_N) {
                int ph = (bin * t) % L_N;             // exact integer phase
                float th = (float)ph * (TWOPI_F / (float)L_N);
                __sincosf(th, &s0, &c0);
            }
            if (t + 1 < L_N) {
                int ph = (bin * (t + 1)) % L_N;
                float th = (float)ph * (TWOPI_F / (float)L_N);
                __sincosf(th, &s1, &c1);
            }
            f16x2 cc = { (f16)c0, (f16)c1 };
            f16x2 ss = { (f16)s0, (f16)s1 };
            *reinterpret_cast<f16x2*>(&W[(size_t)(2 * bin) * KP + t])     = cc;
            *reinterpret_cast<f16x2*>(&W[(size_t)(2 * bin + 1) * KP + t]) = ss;
        }
    } else {
        int i = (b - PB_X - PB_W) * 256 + tid;        // exact: PB_Z*256 slots
        C4[i] = make_float4(0.f, 0.f, 0.f, 0.f);
    }
}

// ------- f16 MFMA GEMM, BK=32, 2-phase dbuf, ZSPLIT=8 (5 blocks/CU exact) -------
// grid (8, 20, 8): z = K-eighth. 128x128 tile, 4 waves (2x2 of 64x64). LDS 32 KB.
// LDS seg-swizzle (validated R4/R5): slot (r,q) holds global seg q ^ ((r>>1)&3)
__global__ __launch_bounds__(256)
void gemm_f16(const f16* __restrict__ A, const f16* __restrict__ W, float* __restrict__ C) {
    __shared__ f16 As[2][128 * 32];
    __shared__ f16 Bs[2][128 * 32];
    const int tid = threadIdx.x;
    const int wv = tid >> 6, lane = tid & 63;
    const int bm = blockIdx.x, bn = blockIdx.y;
    const int ks0 = blockIdx.z * KS_PER_Z;
    const int wr = wv >> 1, wc = wv & 1;
    const int lrow = lane & 15, lseg = lane >> 4;

    f32x4 acc[4][4];
#pragma unroll
    for (int m = 0; m < 4; ++m)
#pragma unroll
        for (int n = 0; n < 4; ++n) acc[m][n] = (f32x4){0.f, 0.f, 0.f, 0.f};

    // staging chunks: chunk c -> LDS slot (R=c>>2, S=c&3); global seg inverse-swizzled
    const int c0 = wv * 128 + lane, c1 = c0 + 64;
    const int R0 = c0 >> 2, S0 = (c0 & 3) ^ ((R0 >> 1) & 3);
    const int R1 = c1 >> 2, S1 = (c1 & 3) ^ ((R1 >> 1) & 3);
    const f16* ga0 = A + (size_t)(bm * 128 + R0) * KP + S0 * 8;
    const f16* ga1 = A + (size_t)(bm * 128 + R1) * KP + S1 * 8;
    const f16* gb0 = W + (size_t)(bn * 128 + R0) * KP + S0 * 8;
    const f16* gb1 = W + (size_t)(bn * 128 + R1) * KP + S1 * 8;

    // K-invariant swizzled LDS read offsets (f16 elem units)
    int aoff[4], boff[4];
#pragma unroll
    for (int m = 0; m < 4; ++m) {
        int ra = wr * 64 + m * 16 + lrow;
        aoff[m] = ra * 32 + ((lseg ^ ((ra >> 1) & 3)) * 8);
        int rb = wc * 64 + m * 16 + lrow;
        boff[m] = rb * 32 + ((lseg ^ ((rb >> 1) & 3)) * 8);
    }

    // prologue: stage K-step 0 into buf 0
    {
        const int kof = ks0 * 32;
        GLOAD16(ga0 + kof, &As[0][c0 * 8]);
        GLOAD16(ga1 + kof, &As[0][c1 * 8]);
        GLOAD16(gb0 + kof, &Bs[0][c0 * 8]);
        GLOAD16(gb1 + kof, &Bs[0][c1 * 8]);
    }
    __syncthreads();                       // drains vmcnt: buf0 ready

    int cur = 0;
    for (int t = 0; t < KS_PER_Z; ++t) {
        const int nxt = cur ^ 1;
        if (t + 1 < KS_PER_Z) {            // issue next-tile loads FIRST (overlap)
            const int kof = (ks0 + t + 1) * 32;
            GLOAD16(ga0 + kof, &As[nxt][c0 * 8]);
            GLOAD16(ga1 + kof, &As[nxt][c1 * 8]);
            GLOAD16(gb0 + kof, &Bs[nxt][c0 * 8]);
            GLOAD16(gb1 + kof, &Bs[nxt][c1 * 8]);
        }
        f16x8 af[4], bf[4];
#pragma unroll
        for (int m = 0; m < 4; ++m) af[m] = *(const f16x8*)&As[cur][aoff[m]];
#pragma unroll
        for (int n = 0; n < 4; ++n) bf[n] = *(const f16x8*)&Bs[cur][boff[n]];
#pragma unroll
        for (int m = 0; m < 4; ++m)
#pragma unroll
            for (int n = 0; n < 4; ++n)
                acc[m][n] = __builtin_amdgcn_mfma_f32_16x16x32_f16(af[m], bf[n], acc[m][n], 0, 0, 0);
        __syncthreads();                   // one barrier/K-step: drains stage, fences reads
        cur = nxt;
    }

    // epilogue: accumulate across z via fp32 atomics (C zero-initialized)
    const int orow0 = bm * 128 + wr * 64 + (lane >> 4) * 4;
    const int ocol0 = bn * 128 + wc * 64 + (lane & 15);
#pragma unroll
    for (int m = 0; m < 4; ++m)
#pragma unroll
        for (int n = 0; n < 4; ++n)
#pragma unroll
            for (int j = 0; j < 4; ++j)
                atomicAdd(&C[(size_t)(orow0 + m * 16 + j) * NB + ocol0 + n * 16], acc[m][n][j]);
}

// ---- fused: per-row top-8 (exact on fp32 keys) + f64 rotation refine + patches ----
// grid B_N, block 512 (8 waves; 1 candidate per wave)
__global__ __launch_bounds__(512)
void fused_sel(const float* __restrict__ x, const float* __restrict__ C,
               const float* __restrict__ wp, float* __restrict__ out) {
    __shared__ float xrow[KP];
    __shared__ unsigned long long keybuf[64];
    __shared__ int bins8s[8];
    __shared__ unsigned long long rk[8];
    const int row = blockIdx.x, tid = threadIdx.x;
    const int wv = tid >> 6, lane = tid & 63;

    if (tid < 60) xrow[2500 + tid] = 0.f;          // pad region
#pragma unroll
    for (int i = 0; i < 2; ++i) {
        int slot = tid + 512 * i;                  // float4 slots 0..624
        if (slot < 625)
            *reinterpret_cast<float4*>(&xrow[slot * 4]) =
                *reinterpret_cast<const float4*>(x + (size_t)row * ROWSTRIDE + slot * 4);
    }

    // power keys: thread covers bins {tid, tid+512, tid+1024}
    unsigned long long k3[3];
#pragma unroll
    for (int c = 0; c < 3; ++c) {
        int bin = tid + 512 * c;
        unsigned long long key = 0ULL;
        if (bin <= 1250) {
            float2 ri = *reinterpret_cast<const float2*>(&C[(size_t)row * NB + 2 * bin]);
            float p = ri.x * ri.x + ri.y * ri.y;
            key = ((unsigned long long)__float_as_uint(p) << 32) | (unsigned)(L_N - bin);
        }
        k3[c] = key;
    }
    // wave-local top-8 (no barriers)
#pragma unroll
    for (int r = 0; r < 8; ++r) {
        unsigned long long m = k3[0];
        m = (k3[1] > m) ? k3[1] : m;
        m = (k3[2] > m) ? k3[2] : m;
#pragma unroll
        for (int off = 32; off > 0; off >>= 1) {
            unsigned long long o = __shfl_xor(m, off, 64);
            m = (o > m) ? o : m;
        }
        if (k3[0] == m) k3[0] = 0ULL;
        if (k3[1] == m) k3[1] = 0ULL;
        if (k3[2] == m) k3[2] = 0ULL;
        if (lane == 0) keybuf[wv * 8 + r] = m;
    }
    __syncthreads();
    // merge 8x8 wave-top8s in wave 0
    if (wv == 0) {
        unsigned long long cur = keybuf[lane];
#pragma unroll
        for (int r = 0; r < 8; ++r) {
            unsigned long long m = cur;
#pragma unroll
            for (int off = 32; off > 0; off >>= 1) {
                unsigned long long o = __shfl_xor(m, off, 64);
                m = (o > m) ? o : m;
            }
            if (cur == m) cur = 0ULL;
            if (lane == 0) bins8s[r] = L_N - (int)(unsigned)(m & 0xffffffffULL);
        }
    }
    __syncthreads();

    // f64 refine of candidate wv: sincos seed + 40-step in-register rotation
    const int k = bins8s[wv];
    double c, s, cd, sd;
    {
        int ph0 = (k * lane) % L_N;
        int phd = (k * 64) % L_N;
        sincos((double)ph0 * RAD_PER_PH, &s, &c);
        sincos((double)phd * RAD_PER_PH, &sd, &cd);
    }
    double re = 0.0, im = 0.0;
#pragma unroll 4
    for (int i = 0; i < 40; ++i) {            // 40*64 == 2560 == KP exactly
        double xv = (double)xrow[lane + 64 * i];
        re += xv * c;
        im += xv * s;
        double cn = c * cd - s * sd;
        double sn = s * cd + c * sd;
        c = cn; s = sn;
    }
#pragma unroll
    for (int off = 32; off > 0; off >>= 1) {
        re += __shfl_xor(re, off, 64);
        im += __shfl_xor(im, off, 64);
    }
    if (lane == 0) {
        double p = re * re + im * im;
        unsigned long long pb = (unsigned long long)__double_as_longlong(p);
        // clear 11 low mantissa bits (rel 2^-41); low field: smaller k wins ties
        rk[wv] = (pb & ~2047ULL) | (unsigned long long)(1250 - k);
    }
    __syncthreads();

    if (tid < NPATCH) {
        unsigned long long q[8];
#pragma unroll
        for (int r = 0; r < 8; ++r) q[r] = rk[r];
        unsigned long long m1 = q[0];
#pragma unroll
        for (int r = 1; r < 8; ++r) m1 = (q[r] > m1) ? q[r] : m1;
#pragma unroll
        for (int r = 0; r < 8; ++r) if (q[r] == m1) q[r] = 0;
        unsigned long long m2 = q[0];
#pragma unroll
        for (int r = 1; r < 8; ++r) m2 = (q[r] > m2) ? q[r] : m2;
#pragma unroll
        for (int r = 0; r < 8; ++r) if (q[r] == m2) q[r] = 0;
        unsigned long long m3 = q[0];
#pragma unroll
        for (int r = 1; r < 8; ++r) m3 = (q[r] > m3) ? q[r] : m3;

        int kA = 1250 - (int)(m1 & 2047ULL);
        int kB = 1250 - (int)(m2 & 2047ULL);
        int kC = 1250 - (int)(m3 & 2047ULL);
        int multA = (kA == 0 || kA == 1250) ? 1 : 2;
        int multB = (kB == 0 || kB == 1250) ? 1 : 2;
        int sel0 = kA;
        int sel1 = (multA == 2 || multB == 2) ? kB : kC;

        int start = tid * PATCH;
        int cnt = 0;
        if (sel0 != 0) {
            int p = L_N / sel0;
            int fm = ((start + p - 1) / p) * p;
            if (fm < start + PATCH) ++cnt;
        }
        if (sel1 != 0) {
            int p = L_N / sel1;
            int fm = ((start + p - 1) / p) * p;
            if (fm < start + PATCH) ++cnt;
        }
        out[(size_t)row * NPATCH + tid] = 12.0f * wp[0] * (float)cnt;
    }
}

extern "C" void kernel_launch(void* const* d_in, const int* in_sizes, int n_in,
                              void* d_out, int out_size, void* d_ws, size_t ws_size,
                              hipStream_t stream) {
    const float* x = (const float*)d_in[0];
    const float* w = (const float*)d_in[1];
    float* out = (float*)d_out;
    char* ws = (char*)d_ws;

    f16* Xh = (f16*)(ws + OFF_XH);
    f16* W  = (f16*)(ws + OFF_W);
    float* C = (float*)(ws + OFF_C);

    prep<<<PB_TOT, 256, 0, stream>>>(x, Xh, W, (float4*)C);
    gemm_f16<<<dim3(8, 20, ZSPLIT), 256, 0, stream>>>(Xh, W, C);
    fused_sel<<<B_N, 512, 0, stream>>>(x, C, w, out);
}

// Round 8
// 208.094 us; speedup vs baseline: 1.2229x; 1.2229x over previous
//
#include <hip/hip_runtime.h>

typedef _Float16 f16;
typedef _Float16 f16x2 __attribute__((ext_vector_type(2)));
typedef _Float16 f16x4 __attribute__((ext_vector_type(4)));
typedef _Float16 f16x8 __attribute__((ext_vector_type(8)));
typedef float f32x4 __attribute__((ext_vector_type(4)));

#define L_N 2500
#define B_N 1024
#define ROWSTRIDE 30000      // 12*2500, channel 0 only
#define NPATCH 50
#define PATCH 50
#define KP 2560              // K padded to 80*32 (pad region zeroed)
#define NB 2560              // 1280 bins * 2 (cos,sin) rows
#define ZSPLIT 4
#define KS_PER_Z 20          // 80 K32-steps / 4

#define TWOPI_F 6.28318530717958647692f
#define RAD_PER_PH (6.283185307179586476925286766559 / 2500.0)

// workspace layout (bytes); total ~60.3 MB (ws is ~491 MB per harness poison size)
#define OFF_XH 0
#define SZ_XH (B_N * KP * 2)              // 5,242,880
#define OFF_W  (OFF_XH + SZ_XH)
#define SZ_W   (NB * KP * 2)              // 13,107,200
#define OFF_P  (OFF_W + SZ_W)
#define SZ_P   (ZSPLIT * B_N * NB * 4)    // 41,943,040 (plain-store partials)

// prep-kernel block ranges (zero_c eliminated — plain stores need no init)
#define PB_X    B_N                    // 1024 blocks: x -> f16
#define PB_W    1280                   // 1280 blocks: twiddles
#define PB_TOT  (PB_X + PB_W)          // 2304

#define GLOAD16(gp, lp) __builtin_amdgcn_global_load_lds( \
    (const __attribute__((address_space(1))) unsigned int*)(gp), \
    (__attribute__((address_space(3))) unsigned int*)(lp), 16, 0, 0)

// ------- fused prep: gen_x | gen_w by blockIdx range -------
__global__ __launch_bounds__(256)
void prep(const float* __restrict__ x, f16* __restrict__ Xh, f16* __restrict__ W) {
    const int b = blockIdx.x, tid = threadIdx.x;
    if (b < PB_X) {
        const int row = b;
#pragma unroll
        for (int i = 0; i < 3; ++i) {
            int slot = tid + 256 * i;                 // float4 slot, 640 per row
            if (slot < 640) {
                float4 v = make_float4(0.f, 0.f, 0.f, 0.f);
                if (slot < 625)                       // 2500/4 == 625 exactly
                    v = *reinterpret_cast<const float4*>(x + (size_t)row * ROWSTRIDE + slot * 4);
                f16x4 h = { (f16)v.x, (f16)v.y, (f16)v.z, (f16)v.w };
                *reinterpret_cast<f16x4*>(Xh + (size_t)row * KP + slot * 4) = h;
            }
        }
    } else {
        const int bin = b - PB_X;                     // 0..1279
#pragma unroll
        for (int i = 0; i < 5; ++i) {                 // KP/2/256 == 5
            int t2 = tid + 256 * i;                   // pair index
            int t = 2 * t2;
            float c0 = 0.f, s0 = 0.f, c1 = 0.f, s1 = 0.f;
            if (t < L_N) {
                int ph = (bin * t) % L_N;             // exact integer phase
                float th = (float)ph * (TWOPI_F / (float)L_N);
                __sincosf(th, &s0, &c0);
            }
            if (t + 1 < L_N) {
                int ph = (bin * (t + 1)) % L_N;
                float th = (float)ph * (TWOPI_F / (float)L_N);
                __sincosf(th, &s1, &c1);
            }
            f16x2 cc = { (f16)c0, (f16)c1 };
            f16x2 ss = { (f16)s0, (f16)s1 };
            *reinterpret_cast<f16x2*>(&W[(size_t)(2 * bin) * KP + t])     = cc;
            *reinterpret_cast<f16x2*>(&W[(size_t)(2 * bin + 1) * KP + t]) = ss;
        }
    }
}

// ------- f16 MFMA GEMM, BK=32, 2-phase dbuf, PLAIN-STORE partials (no atomics) -------
// grid (8, 20, 4): z = K-quarter -> its own partial buffer. 128x128 tile, 4 waves.
// LDS seg-swizzle (validated R4/R5): slot (r,q) holds global seg q ^ ((r>>1)&3)
__global__ __launch_bounds__(256)
void gemm_f16(const f16* __restrict__ A, const f16* __restrict__ W, float* __restrict__ P) {
    __shared__ f16 As[2][128 * 32];
    __shared__ f16 Bs[2][128 * 32];
    const int tid = threadIdx.x;
    const int wv = tid >> 6, lane = tid & 63;
    const int bm = blockIdx.x, bn = blockIdx.y;
    const int ks0 = blockIdx.z * KS_PER_Z;
    const int wr = wv >> 1, wc = wv & 1;
    const int lrow = lane & 15, lseg = lane >> 4;

    f32x4 acc[4][4];
#pragma unroll
    for (int m = 0; m < 4; ++m)
#pragma unroll
        for (int n = 0; n < 4; ++n) acc[m][n] = (f32x4){0.f, 0.f, 0.f, 0.f};

    // staging chunks: chunk c -> LDS slot (R=c>>2, S=c&3); global seg inverse-swizzled
    const int c0 = wv * 128 + lane, c1 = c0 + 64;
    const int R0 = c0 >> 2, S0 = (c0 & 3) ^ ((R0 >> 1) & 3);
    const int R1 = c1 >> 2, S1 = (c1 & 3) ^ ((R1 >> 1) & 3);
    const f16* ga0 = A + (size_t)(bm * 128 + R0) * KP + S0 * 8;
    const f16* ga1 = A + (size_t)(bm * 128 + R1) * KP + S1 * 8;
    const f16* gb0 = W + (size_t)(bn * 128 + R0) * KP + S0 * 8;
    const f16* gb1 = W + (size_t)(bn * 128 + R1) * KP + S1 * 8;

    // K-invariant swizzled LDS read offsets (f16 elem units)
    int aoff[4], boff[4];
#pragma unroll
    for (int m = 0; m < 4; ++m) {
        int ra = wr * 64 + m * 16 + lrow;
        aoff[m] = ra * 32 + ((lseg ^ ((ra >> 1) & 3)) * 8);
        int rb = wc * 64 + m * 16 + lrow;
        boff[m] = rb * 32 + ((lseg ^ ((rb >> 1) & 3)) * 8);
    }

    // prologue: stage K-step 0 into buf 0
    {
        const int kof = ks0 * 32;
        GLOAD16(ga0 + kof, &As[0][c0 * 8]);
        GLOAD16(ga1 + kof, &As[0][c1 * 8]);
        GLOAD16(gb0 + kof, &Bs[0][c0 * 8]);
        GLOAD16(gb1 + kof, &Bs[0][c1 * 8]);
    }
    __syncthreads();                       // drains vmcnt: buf0 ready

    int cur = 0;
    for (int t = 0; t < KS_PER_Z; ++t) {
        const int nxt = cur ^ 1;
        if (t + 1 < KS_PER_Z) {            // issue next-tile loads FIRST (overlap)
            const int kof = (ks0 + t + 1) * 32;
            GLOAD16(ga0 + kof, &As[nxt][c0 * 8]);
            GLOAD16(ga1 + kof, &As[nxt][c1 * 8]);
            GLOAD16(gb0 + kof, &Bs[nxt][c0 * 8]);
            GLOAD16(gb1 + kof, &Bs[nxt][c1 * 8]);
        }
        f16x8 af[4], bf[4];
#pragma unroll
        for (int m = 0; m < 4; ++m) af[m] = *(const f16x8*)&As[cur][aoff[m]];
#pragma unroll
        for (int n = 0; n < 4; ++n) bf[n] = *(const f16x8*)&Bs[cur][boff[n]];
#pragma unroll
        for (int m = 0; m < 4; ++m)
#pragma unroll
            for (int n = 0; n < 4; ++n)
                acc[m][n] = __builtin_amdgcn_mfma_f32_16x16x32_f16(af[m], bf[n], acc[m][n], 0, 0, 0);
        __syncthreads();                   // one barrier/K-step: drains stage, fences reads
        cur = nxt;
    }

    // epilogue: plain coalesced stores into this z-slice's partial buffer
    float* Pz = P + (size_t)blockIdx.z * B_N * NB;
    const int orow0 = bm * 128 + wr * 64 + (lane >> 4) * 4;
    const int ocol0 = bn * 128 + wc * 64 + (lane & 15);
#pragma unroll
    for (int m = 0; m < 4; ++m)
#pragma unroll
        for (int n = 0; n < 4; ++n)
#pragma unroll
            for (int j = 0; j < 4; ++j)
                Pz[(size_t)(orow0 + m * 16 + j) * NB + ocol0 + n * 16] = acc[m][n][j];
}

// ---- fused: sum partials -> per-row top-8 (exact fp32 keys) + f64 refine + patches ----
// grid B_N, block 512 (8 waves; 1 candidate per wave)
__global__ __launch_bounds__(512)
void fused_sel(const float* __restrict__ x, const float* __restrict__ P,
               const float* __restrict__ wp, float* __restrict__ out) {
    __shared__ float xrow[KP];
    __shared__ unsigned long long keybuf[64];
    __shared__ int bins8s[8];
    __shared__ unsigned long long rk[8];
    const int row = blockIdx.x, tid = threadIdx.x;
    const int wv = tid >> 6, lane = tid & 63;

    if (tid < 60) xrow[2500 + tid] = 0.f;          // pad region
#pragma unroll
    for (int i = 0; i < 2; ++i) {
        int slot = tid + 512 * i;                  // float4 slots 0..624
        if (slot < 625)
            *reinterpret_cast<float4*>(&xrow[slot * 4]) =
                *reinterpret_cast<const float4*>(x + (size_t)row * ROWSTRIDE + slot * 4);
    }

    // power keys: thread covers bins {tid, tid+512, tid+1024}; sum 4 partials
    unsigned long long k3[3];
#pragma unroll
    for (int c = 0; c < 3; ++c) {
        int bin = tid + 512 * c;
        unsigned long long key = 0ULL;
        if (bin <= 1250) {
            float re = 0.f, im = 0.f;
#pragma unroll
            for (int s2 = 0; s2 < ZSPLIT; ++s2) {
                float2 ri = *reinterpret_cast<const float2*>(
                    &P[((size_t)s2 * B_N + row) * NB + 2 * bin]);
                re += ri.x; im += ri.y;
            }
            float p = re * re + im * im;
            key = ((unsigned long long)__float_as_uint(p) << 32) | (unsigned)(L_N - bin);
        }
        k3[c] = key;
    }
    // wave-local top-8 (no barriers)
#pragma unroll
    for (int r = 0; r < 8; ++r) {
        unsigned long long m = k3[0];
        m = (k3[1] > m) ? k3[1] : m;
        m = (k3[2] > m) ? k3[2] : m;
#pragma unroll
        for (int off = 32; off > 0; off >>= 1) {
            unsigned long long o = __shfl_xor(m, off, 64);
            m = (o > m) ? o : m;
        }
        if (k3[0] == m) k3[0] = 0ULL;
        if (k3[1] == m) k3[1] = 0ULL;
        if (k3[2] == m) k3[2] = 0ULL;
        if (lane == 0) keybuf[wv * 8 + r] = m;
    }
    __syncthreads();
    // merge 8x8 wave-top8s in wave 0
    if (wv == 0) {
        unsigned long long cur = keybuf[lane];
#pragma unroll
        for (int r = 0; r < 8; ++r) {
            unsigned long long m = cur;
#pragma unroll
            for (int off = 32; off > 0; off >>= 1) {
                unsigned long long o = __shfl_xor(m, off, 64);
                m = (o > m) ? o : m;
            }
            if (cur == m) cur = 0ULL;
            if (lane == 0) bins8s[r] = L_N - (int)(unsigned)(m & 0xffffffffULL);
        }
    }
    __syncthreads();

    // f64 refine of candidate wv: sincos seed + 40-step in-register rotation
    const int k = bins8s[wv];
    double c, s, cd, sd;
    {
        int ph0 = (k * lane) % L_N;
        int phd = (k * 64) % L_N;
        sincos((double)ph0 * RAD_PER_PH, &s, &c);
        sincos((double)phd * RAD_PER_PH, &sd, &cd);
    }
    double re = 0.0, im = 0.0;
#pragma unroll 4
    for (int i = 0; i < 40; ++i) {            // 40*64 == 2560 == KP exactly
        double xv = (double)xrow[lane + 64 * i];
        re += xv * c;
        im += xv * s;
        double cn = c * cd - s * sd;
        double sn = s * cd + c * sd;
        c = cn; s = sn;
    }
#pragma unroll
    for (int off = 32; off > 0; off >>= 1) {
        re += __shfl_xor(re, off, 64);
        im += __shfl_xor(im, off, 64);
    }
    if (lane == 0) {
        double p = re * re + im * im;
        unsigned long long pb = (unsigned long long)__double_as_longlong(p);
        // clear 11 low mantissa bits (rel 2^-41); low field: smaller k wins ties
        rk[wv] = (pb & ~2047ULL) | (unsigned long long)(1250 - k);
    }
    __syncthreads();

    if (tid < NPATCH) {
        unsigned long long q[8];
#pragma unroll
        for (int r = 0; r < 8; ++r) q[r] = rk[r];
        unsigned long long m1 = q[0];
#pragma unroll
        for (int r = 1; r < 8; ++r) m1 = (q[r] > m1) ? q[r] : m1;
#pragma unroll
        for (int r = 0; r < 8; ++r) if (q[r] == m1) q[r] = 0;
        unsigned long long m2 = q[0];
#pragma unroll
        for (int r = 1; r < 8; ++r) m2 = (q[r] > m2) ? q[r] : m2;
#pragma unroll
        for (int r = 0; r < 8; ++r) if (q[r] == m2) q[r] = 0;
        unsigned long long m3 = q[0];
#pragma unroll
        for (int r = 1; r < 8; ++r) m3 = (q[r] > m3) ? q[r] : m3;

        int kA = 1250 - (int)(m1 & 2047ULL);
        int kB = 1250 - (int)(m2 & 2047ULL);
        int kC = 1250 - (int)(m3 & 2047ULL);
        int multA = (kA == 0 || kA == 1250) ? 1 : 2;
        int multB = (kB == 0 || kB == 1250) ? 1 : 2;
        int sel0 = kA;
        int sel1 = (multA == 2 || multB == 2) ? kB : kC;

        int start = tid * PATCH;
        int cnt = 0;
        if (sel0 != 0) {
            int p = L_N / sel0;
            int fm = ((start + p - 1) / p) * p;
            if (fm < start + PATCH) ++cnt;
        }
        if (sel1 != 0) {
            int p = L_N / sel1;
            int fm = ((start + p - 1) / p) * p;
            if (fm < start + PATCH) ++cnt;
        }
        out[(size_t)row * NPATCH + tid] = 12.0f * wp[0] * (float)cnt;
    }
}

extern "C" void kernel_launch(void* const* d_in, const int* in_sizes, int n_in,
                              void* d_out, int out_size, void* d_ws, size_t ws_size,
                              hipStream_t stream) {
    const float* x = (const float*)d_in[0];
    const float* w = (const float*)d_in[1];
    float* out = (float*)d_out;
    char* ws = (char*)d_ws;

    f16* Xh = (f16*)(ws + OFF_XH);
    f16* W  = (f16*)(ws + OFF_W);
    float* P = (float*)(ws + OFF_P);

    prep<<<PB_TOT, 256, 0, stream>>>(x, Xh, W);
    gemm_f16<<<dim3(8, 20, ZSPLIT), 256, 0, stream>>>(Xh, W, P);
    fused_sel<<<B_N, 512, 0, stream>>>(x, P, w, out);
}